// Round 12
// baseline (274.736 us; speedup 1.0000x reference)
//
#include <hip/hip_runtime.h>

typedef unsigned short u16;
typedef unsigned int   u32;
typedef short bf16x8 __attribute__((ext_vector_type(8)));
typedef float f32x4  __attribute__((ext_vector_type(4)));
typedef float f32x2  __attribute__((ext_vector_type(2)));

#define BG    128      // graphs
#define NN    128      // nodes per graph
#define MS    16       // samples
#define KP    8        // pearl_k
#define HM    16       // mlp hidden
#define DP    64       // pe dims
#define NSUM  16384    // BG*NN
#define NE    262144   // edges
#define SITES 2048     // NN*MS

// R3: inputs f32, output f32. Intermediates bf16.
// R10: poly = MFMA split-precision. R11: agg2 m-sliced persistent-chunk
//   (76.5->53.7us, FETCH 248->67MB) — structure PROVEN.
// R12: same structure for agg1 (h1 stored transposed h1T[m][node][c];
//   slice 512KB -> L2-resident). z1 stays row-major so mm1 unchanged.

__device__ __forceinline__ float blo(u32 u){ union{u32 i; float f;} v; v.i=u<<16; return v.f; }
__device__ __forceinline__ float bhi(u32 u){ union{u32 i; float f;} v; v.i=u&0xffff0000u; return v.f; }
__device__ __forceinline__ u16  f2b(float f){ union{float f; u32 i;} v; v.f=f; u32 x=v.i; x += 0x7fffu + ((x>>16)&1u); return (u16)(x>>16); }
__device__ __forceinline__ u32  pk2(float a, float b){ return (u32)f2b(a) | ((u32)f2b(b)<<16); }
__device__ __forceinline__ f32x2 up2(u32 u){ f32x2 v; v.x=blo(u); v.y=bhi(u); return v; }

__device__ __forceinline__ void fsplit(float x, short& hi, short& lo){
  u16 h = f2b(x); hi = (short)h; lo = (short)f2b(x - blo((u32)h));
}

#define MFMA16(a,b,c) __builtin_amdgcn_mfma_f32_16x16x32_bf16(a,b,c,0,0,0)

__device__ __forceinline__ bf16x8 bfragW(const float* __restrict__ W, int nrows,
                                         int k0, int nb, int col, int quad){
  bf16x8 f;
  #pragma unroll
  for(int j=0;j<8;++j){
    int k = k0 + quad*8 + j;
    float v = (k < nrows) ? W[k*DP + nb + col] : 0.f;
    f[j] = (short)f2b(v);
  }
  return f;
}
__device__ __forceinline__ bf16x8 afragT(const float* tp){
  float4 v0 = *(const float4*)tp;
  float4 v1 = *(const float4*)(tp+4);
  bf16x8 a;
  a[0]=(short)f2b(v0.x); a[1]=(short)f2b(v0.y); a[2]=(short)f2b(v0.z); a[3]=(short)f2b(v0.w);
  a[4]=(short)f2b(v1.x); a[5]=(short)f2b(v1.y); a[6]=(short)f2b(v1.z); a[7]=(short)f2b(v1.w);
  return a;
}

// ---------------------------------------------------------------------------
// K1: poly filter via MFMA split-precision (R10). Writes h1 TRANSPOSED:
// h1T[m][node][c] (32B contiguous per site; same pattern as R6's poly).
// ---------------------------------------------------------------------------
__global__ __launch_bounds__(256,1) void k_poly(
    const float* __restrict__ lap, const float* __restrict__ W0, const float* __restrict__ mlpW,
    const float* __restrict__ bng, const float* __restrict__ bnb, u16* __restrict__ h1T,
    int* __restrict__ cnt)
{
  __shared__ float Wbuf[2][SITES];
  __shared__ float mlpWS[KP*HM];
  __shared__ float red[4][32];
  __shared__ float stat[32];
  __shared__ float ssc[HM], ssh[HM];

  const int b = blockIdx.x, t = threadIdx.x, l = t&63, w = t>>6;
  const int col = l&15, quad = l>>4;
  if (t < 128) cnt[b*128 + t] = 0;

  {
    const float4* src = (const float4*)(W0 + (size_t)b*SITES);
    for (int i=t; i<SITES/4; i+=256) ((float4*)Wbuf[0])[i] = src[i];
    if (t < KP*HM) mlpWS[t] = mlpW[t];
  }

  bf16x8 Ah[2][4], Al[2][4];
  {
    const float* lg = lap + (size_t)b*NN*NN;
    #pragma unroll
    for(int Mt=0;Mt<2;++Mt){
      const int nr = w*32 + Mt*16 + col;
      #pragma unroll
      for(int Kc=0;Kc<4;++Kc){
        const float* p = lg + (size_t)nr*NN + Kc*32 + quad*8;
        float4 v0 = *(const float4*)p;
        float4 v1 = *(const float4*)(p+4);
        float xs[8] = {v0.x,v0.y,v0.z,v0.w,v1.x,v1.y,v1.z,v1.w};
        #pragma unroll
        for(int j=0;j<8;++j){ short hi,lo; fsplit(xs[j],hi,lo); Ah[Mt][Kc][j]=hi; Al[Mt][Kc][j]=lo; }
      }
    }
  }

  float h[8][16];
  {
    const float* w0g = W0 + (size_t)b*SITES;
    #pragma unroll
    for(int Mt=0;Mt<2;++Mt){
      #pragma unroll
      for(int r=0;r<4;++r){
        const int n = w*32 + Mt*16 + quad*4 + r;
        float sv = w0g[n*MS + col];
        #pragma unroll
        for(int c=0;c<16;++c) h[Mt*4+r][c] = sv*mlpW[c];
      }
    }
  }
  __syncthreads();

  int cur=0;
  for(int k=1;k<KP;++k){
    f32x4 c0 = {0.f,0.f,0.f,0.f};
    f32x4 c1 = {0.f,0.f,0.f,0.f};
    #pragma unroll
    for(int Kc=0;Kc<4;++Kc){
      const float* wb = &Wbuf[cur][(Kc*32 + quad*8)*MS + col];
      bf16x8 Bh, Bl;
      #pragma unroll
      for(int j=0;j<8;++j){
        float x = wb[j*MS];
        short hi,lo; fsplit(x,hi,lo); Bh[j]=hi; Bl[j]=lo;
      }
      c0 = MFMA16(Ah[0][Kc], Bh, c0);
      c0 = MFMA16(Ah[0][Kc], Bl, c0);
      c0 = MFMA16(Al[0][Kc], Bh, c0);
      c1 = MFMA16(Ah[1][Kc], Bh, c1);
      c1 = MFMA16(Ah[1][Kc], Bl, c1);
      c1 = MFMA16(Al[1][Kc], Bh, c1);
    }
    float mw[16];
    #pragma unroll
    for(int c=0;c<16;++c) mw[c]=mlpWS[k*16+c];
    #pragma unroll
    for(int r=0;r<4;++r){
      const int n0 = w*32 + quad*4 + r;
      Wbuf[cur^1][n0*MS + col]        = c0[r];
      Wbuf[cur^1][(n0+16)*MS + col]   = c1[r];
      #pragma unroll
      for(int c=0;c<16;++c){ h[r][c] += c0[r]*mw[c]; h[4+r][c] += c1[r]*mw[c]; }
    }
    __syncthreads();
    cur ^= 1;
  }

  float sum[16], sq[16];
  #pragma unroll
  for(int c=0;c<16;++c){ sum[c]=0.f; sq[c]=0.f; }
  #pragma unroll
  for(int s=0;s<8;++s){
    #pragma unroll
    for(int c=0;c<16;++c){ float v=h[s][c]; sum[c]+=v; sq[c]+=v*v; }
  }
  #pragma unroll
  for(int d=1;d<64;d<<=1){
    #pragma unroll
    for(int c=0;c<16;++c){ sum[c]+=__shfl_xor(sum[c],d,64); sq[c]+=__shfl_xor(sq[c],d,64); }
  }
  if(l==0){
    #pragma unroll
    for(int c=0;c<16;++c){ red[w][c]=sum[c]; red[w][16+c]=sq[c]; }
  }
  __syncthreads();
  if(t<32) stat[t]=red[0][t]+red[1][t]+red[2][t]+red[3][t];
  __syncthreads();
  if(t<16){
    float mu  = stat[t]*(1.f/SITES);
    float var = stat[16+t]*(1.f/SITES) - mu*mu;
    float sc  = bng[t] * rsqrtf(var + 1e-5f);
    ssc[t]=sc; ssh[t]=bnb[t] - mu*sc;
  }
  __syncthreads();
  {
    float sc[16], sh[16];
    #pragma unroll
    for(int c=0;c<16;++c){ sc[c]=ssc[c]; sh[c]=ssh[c]; }
    #pragma unroll
    for(int s=0;s<8;++s){
      const int n = w*32 + (s>>2)*16 + quad*4 + (s&3);
      const int node = b*NN + n;
      float r[16];
      #pragma unroll
      for(int c=0;c<16;++c) r[c]=fmaxf(h[s][c]*sc[c]+sh[c], 0.f);
      uint4 A;
      A.x=pk2(r[0],r[1]);  A.y=pk2(r[2],r[3]);  A.z=pk2(r[4],r[5]);  A.w=pk2(r[6],r[7]);
      uint4 Bv;
      Bv.x=pk2(r[8],r[9]); Bv.y=pk2(r[10],r[11]); Bv.z=pk2(r[12],r[13]); Bv.w=pk2(r[14],r[15]);
      u16* o = h1T + ((size_t)col*NSUM + node)*HM;
      *(uint4*)o     = A;
      *(uint4*)(o+8) = Bv;
    }
  }
}

// --------------------------- CSR build (by dst) ----------------------------
__global__ void k_hist(const int* __restrict__ dst, int* __restrict__ cnt){
  int e = blockIdx.x*256 + threadIdx.x;
  atomicAdd(&cnt[dst[e]], 1);
}

__global__ void k_scan(const int* __restrict__ cnt, int* __restrict__ off, int* __restrict__ wpos){
  __shared__ int ps[256];
  const int t = threadIdx.x, PER = NSUM/256;
  int s=0;
  for(int i=0;i<PER;++i) s += cnt[t*PER+i];
  ps[t]=s; __syncthreads();
  for(int d=1; d<256; d<<=1){
    int v = (t>=d) ? ps[t-d] : 0;
    __syncthreads();
    ps[t] += v;
    __syncthreads();
  }
  int run = (t==0) ? 0 : ps[t-1];
  for(int i=0;i<PER;++i){
    int idx=t*PER+i;
    off[idx]=run; wpos[idx]=run;
    run += cnt[idx];
  }
  if(t==255) off[NSUM]=run;
}

__global__ void k_scatter(const int* __restrict__ srcI, const int* __restrict__ dstI,
                          int* __restrict__ wpos, int* __restrict__ srcs){
  int e = blockIdx.x*256 + threadIdx.x;
  int p = atomicAdd(&wpos[dstI[e]], 1);
  srcs[p] = srcI[e];
}

// ---------------------------------------------------------------------------
// K4a: GIN-1 aggregate, m-sliced + persistent chunk ownership (R11 agg2
// structure). Block: m = blockIdx&15 (slice 512KB, L2-resident), 4 waves x
// 16 nodes. Lane: grp=l>>2 (node), q=l&3 (8B chunk of 32B slice). One
// dwordx2 wave-inst = 16 edges. Wave-max degree loop + scale-predication.
// z1 written row-major [node][m][c] -> mm1 unchanged.
// ---------------------------------------------------------------------------
__global__ __launch_bounds__(256) void k_agg1(
  const u16* __restrict__ h1T, const float* __restrict__ eps1p,
  const int* __restrict__ off, const int* __restrict__ srcs, u16* __restrict__ z1)
{
  const int t=threadIdx.x, l=t&63, w=t>>6;
  const int m = blockIdx.x & 15, g = blockIdx.x >> 4;
  const int grp = l>>2, q = l&3;
  const int node = g*64 + w*16 + grp;
  const float epe = 1.f + eps1p[0];
  const u16* __restrict__ base = h1T + (size_t)m*NSUM*HM;

  f32x2 A[2];
  {
    uint2 x = *(const uint2*)&base[(size_t)node*HM + q*4];
    f32x2 s2; s2.x=epe; s2.y=epe;
    A[0]=s2*up2(x.x); A[1]=s2*up2(x.y);
  }
  const int e0 = off[node], e1 = off[node+1];
  int dmax = e1 - e0;
  #pragma unroll
  for(int d=1; d<64; d<<=1) dmax = max(dmax, __shfl_xor(dmax, d, 64));

  int i = 0;
  for(; i+2 <= dmax; i += 2){
    int pa = e0+i, pb = e0+i+1;
    float sa = (pa < e1) ? 1.f : 0.f;
    float sb = (pb < e1) ? 1.f : 0.f;
    int ea = min(pa, NE-1), eb = min(pb, NE-1);
    int ia = srcs[ea], ib = srcs[eb];
    uint2 xa = *(const uint2*)&base[(size_t)ia*HM + q*4];
    uint2 xb = *(const uint2*)&base[(size_t)ib*HM + q*4];
    f32x2 va; va.x=sa; va.y=sa;
    f32x2 vb; vb.x=sb; vb.y=sb;
    A[0]+=va*up2(xa.x); A[1]+=va*up2(xa.y);
    A[0]+=vb*up2(xb.x); A[1]+=vb*up2(xb.y);
  }
  if(i < dmax){
    int pa = e0+i;
    float sa = (pa < e1) ? 1.f : 0.f;
    int ea = min(pa, NE-1);
    int ia = srcs[ea];
    uint2 xa = *(const uint2*)&base[(size_t)ia*HM + q*4];
    f32x2 va; va.x=sa; va.y=sa;
    A[0]+=va*up2(xa.x); A[1]+=va*up2(xa.y);
  }

  uint2 o; o.x=pk2(A[0].x,A[0].y); o.y=pk2(A[1].x,A[1].y);
  *(uint2*)&z1[(size_t)node*256 + m*HM + q*4] = o;
}

// ---------------------------------------------------------------------------
// K5a: GIN-2 aggregate, m-sliced + persistent chunk ownership (R11, proven).
// ---------------------------------------------------------------------------
__global__ __launch_bounds__(256) void k_agg2(
  const u16* __restrict__ h2T, const float* __restrict__ eps2p,
  const int* __restrict__ off, const int* __restrict__ srcs, u16* __restrict__ z2)
{
  const int t=threadIdx.x, l=t&63, w=t>>6;
  const int m = blockIdx.x & 15, g = blockIdx.x >> 4;
  const int grp = l>>3, q = l&7;
  const int node = g*32 + w*8 + grp;
  const float epe = 1.f + eps2p[0];
  const u16* __restrict__ base = h2T + (size_t)m*NSUM*DP;

  f32x2 A[4];
  {
    uint4 x = *(const uint4*)&base[(size_t)node*DP + q*8];
    f32x2 s2; s2.x=epe; s2.y=epe;
    A[0]=s2*up2(x.x); A[1]=s2*up2(x.y); A[2]=s2*up2(x.z); A[3]=s2*up2(x.w);
  }
  const int e0 = off[node], e1 = off[node+1];
  int dmax = e1 - e0;
  #pragma unroll
  for(int d=1; d<64; d<<=1) dmax = max(dmax, __shfl_xor(dmax, d, 64));

  int i = 0;
  for(; i+2 <= dmax; i += 2){
    int pa = e0+i, pb = e0+i+1;
    float sa = (pa < e1) ? 1.f : 0.f;
    float sb = (pb < e1) ? 1.f : 0.f;
    int ea = min(pa, NE-1), eb = min(pb, NE-1);
    int ia = srcs[ea], ib = srcs[eb];
    uint4 xa = *(const uint4*)&base[(size_t)ia*DP + q*8];
    uint4 xb = *(const uint4*)&base[(size_t)ib*DP + q*8];
    f32x2 va; va.x=sa; va.y=sa;
    f32x2 vb; vb.x=sb; vb.y=sb;
    A[0]+=va*up2(xa.x); A[1]+=va*up2(xa.y); A[2]+=va*up2(xa.z); A[3]+=va*up2(xa.w);
    A[0]+=vb*up2(xb.x); A[1]+=vb*up2(xb.y); A[2]+=vb*up2(xb.z); A[3]+=vb*up2(xb.w);
  }
  if(i < dmax){
    int pa = e0+i;
    float sa = (pa < e1) ? 1.f : 0.f;
    int ea = min(pa, NE-1);
    int ia = srcs[ea];
    uint4 xa = *(const uint4*)&base[(size_t)ia*DP + q*8];
    f32x2 va; va.x=sa; va.y=sa;
    A[0]+=va*up2(xa.x); A[1]+=va*up2(xa.y); A[2]+=va*up2(xa.z); A[3]+=va*up2(xa.w);
  }

  uint4 o;
  o.x=pk2(A[0].x,A[0].y); o.y=pk2(A[1].x,A[1].y);
  o.z=pk2(A[2].x,A[2].y); o.w=pk2(A[3].x,A[3].y);
  *(uint4*)&z2[(size_t)node*1024 + m*DP + q*8] = o;
}

// ---------------------------------------------------------------------------
// K4b: GIN-1 MLP via MFMA; writes h2 TRANSPOSED h2T[m][node][d].
// ---------------------------------------------------------------------------
__global__ __launch_bounds__(256) void k_mm1(
  const u16* __restrict__ z1, const float* __restrict__ W1a, const float* __restrict__ b1a,
  const float* __restrict__ W1b, const float* __restrict__ b1b, u16* __restrict__ h2T)
{
  __shared__ float tS[4][16*68 + 4];
  const int t=threadIdx.x, l=t&63, w=t>>6;
  const int col=l&15, quad=l>>4;

  bf16x8 fa[4], fb[4][2];
  float bav[4], bbv[4];
  #pragma unroll
  for(int nt=0;nt<4;++nt){
    fa[nt]    = bfragW(W1a, HM, 0,  nt*16, col, quad);   // k>=16 zeroed
    fb[nt][0] = bfragW(W1b, DP, 0,  nt*16, col, quad);
    fb[nt][1] = bfragW(W1b, DP, 32, nt*16, col, quad);
    bav[nt] = b1a[nt*16+col];
    bbv[nt] = b1b[nt*16+col];
  }
  for(int ni=0;ni<2;++ni){
    const int node = blockIdx.x*8 + ni*4 + w;
    bf16x8 a0;
    #pragma unroll
    for(int j=0;j<8;++j) a0[j]=0;
    if (quad < 2) a0 = *(const bf16x8*)&z1[(size_t)node*256 + col*16 + quad*8];
    #pragma unroll
    for(int nt=0;nt<4;++nt){
      f32x4 c = {bav[nt], bav[nt], bav[nt], bav[nt]};
      c = MFMA16(a0, fa[nt], c);
      #pragma unroll
      for(int r=0;r<4;++r)
        tS[w][(quad*4+r)*68 + nt*16 + col] = fmaxf(c[r], 0.f);
    }
    bf16x8 ta0 = afragT(&tS[w][col*68 + quad*8]);
    bf16x8 ta1 = afragT(&tS[w][col*68 + 32 + quad*8]);
    #pragma unroll
    for(int nt=0;nt<4;++nt){
      f32x4 c = {bbv[nt], bbv[nt], bbv[nt], bbv[nt]};
      c = MFMA16(ta0, fb[nt][0], c);
      c = MFMA16(ta1, fb[nt][1], c);
      #pragma unroll
      for(int r=0;r<4;++r)
        h2T[((size_t)(quad*4+r)*NSUM + node)*DP + nt*16 + col] = f2b(fmaxf(c[r], 0.f));
    }
  }
}

// ---------------------------------------------------------------------------
// K5b: GIN-2 MLP via MFMA + ReLU + sum over M -> out f32 [NSUM,64].
// ---------------------------------------------------------------------------
__global__ __launch_bounds__(256) void k_mm2(
  const u16* __restrict__ z2, const float* __restrict__ W2a, const float* __restrict__ b2a,
  const float* __restrict__ W2b, const float* __restrict__ b2b, float* __restrict__ out)
{
  __shared__ float tS[4][16*68 + 4];
  const int t=threadIdx.x, l=t&63, w=t>>6;
  const int col=l&15, quad=l>>4;

  bf16x8 fa[4][2], fb[4][2];
  float bav[4], bbv[4];
  #pragma unroll
  for(int nt=0;nt<4;++nt){
    fa[nt][0] = bfragW(W2a, DP, 0,  nt*16, col, quad);
    fa[nt][1] = bfragW(W2a, DP, 32, nt*16, col, quad);
    fb[nt][0] = bfragW(W2b, DP, 0,  nt*16, col, quad);
    fb[nt][1] = bfragW(W2b, DP, 32, nt*16, col, quad);
    bav[nt] = b2a[nt*16+col];
    bbv[nt] = b2b[nt*16+col];
  }
  for(int ni=0;ni<2;++ni){
    const int node = blockIdx.x*8 + ni*4 + w;
    const u16* zrow = &z2[(size_t)node*1024];
    bf16x8 a0 = *(const bf16x8*)&zrow[col*64 + quad*8];
    bf16x8 a1 = *(const bf16x8*)&zrow[col*64 + quad*8 + 32];
    #pragma unroll
    for(int nt=0;nt<4;++nt){
      f32x4 c = {bav[nt], bav[nt], bav[nt], bav[nt]};
      c = MFMA16(a0, fa[nt][0], c);
      c = MFMA16(a1, fa[nt][1], c);
      #pragma unroll
      for(int r=0;r<4;++r)
        tS[w][(quad*4+r)*68 + nt*16 + col] = fmaxf(c[r], 0.f);
    }
    bf16x8 ta0 = afragT(&tS[w][col*68 + quad*8]);
    bf16x8 ta1 = afragT(&tS[w][col*68 + 32 + quad*8]);
    #pragma unroll
    for(int nt=0;nt<4;++nt){
      f32x4 c = {bbv[nt], bbv[nt], bbv[nt], bbv[nt]};
      c = MFMA16(ta0, fb[nt][0], c);
      c = MFMA16(ta1, fb[nt][1], c);
      float s = fmaxf(c[0],0.f)+fmaxf(c[1],0.f)+fmaxf(c[2],0.f)+fmaxf(c[3],0.f);
      s += __shfl_xor(s, 16, 64);
      s += __shfl_xor(s, 32, 64);
      if (quad == 0)
        out[(size_t)node*64 + nt*16 + col] = s;
    }
  }
}

extern "C" void kernel_launch(void* const* d_in, const int* in_sizes, int n_in,
                              void* d_out, int out_size, void* d_ws, size_t ws_size,
                              hipStream_t stream)
{
  (void)in_sizes; (void)n_in; (void)out_size; (void)ws_size;
  const float* lap  = (const float*)d_in[0];
  const float* W0   = (const float*)d_in[1];
  const float* mlpW = (const float*)d_in[2];
  // d_in[3] = mlp_b: cancels inside BatchNorm (pure mean shift)
  const float* bng  = (const float*)d_in[4];
  const float* bnb  = (const float*)d_in[5];
  const float* eps1 = (const float*)d_in[6];
  const float* W1a  = (const float*)d_in[7];
  const float* b1a  = (const float*)d_in[8];
  const float* W1b  = (const float*)d_in[9];
  const float* b1b  = (const float*)d_in[10];
  const float* eps2 = (const float*)d_in[11];
  const float* W2a  = (const float*)d_in[12];
  const float* b2a  = (const float*)d_in[13];
  const float* W2b  = (const float*)d_in[14];
  const float* b2b  = (const float*)d_in[15];
  const int*   ei   = (const int*)d_in[16];
  const int* srcI = ei;
  const int* dstI = ei + NE;

  char* ws = (char*)d_ws;
  u16* h1T  = (u16*)(ws);                    //  8,388,608 B  [16][16384][16]
  u16* z1   = (u16*)(ws + 8388608);          //  8,388,608 B  [16384][16][16]
  u16* h2T  = (u16*)(ws + 16777216);         // 33,554,432 B  [16][16384][64]
  u16* z2   = (u16*)(ws + 50331648);         // 33,554,432 B  [16384][16][64]
  int* cnt  = (int*)(ws + 83886080);         //     65,536 B
  int* offA = (int*)(ws + 83951616);         //     65,792 B
  int* wpos = (int*)(ws + 84017408);         //     65,536 B
  int* srcs = (int*)(ws + 84082944);         //  1,048,576 B  (end 85,131,520)

  k_poly   <<<BG,      256, 0, stream>>>(lap, W0, mlpW, bng, bnb, h1T, cnt);
  k_hist   <<<NE/256,  256, 0, stream>>>(dstI, cnt);
  k_scan   <<<1,       256, 0, stream>>>(cnt, offA, wpos);
  k_scatter<<<NE/256,  256, 0, stream>>>(srcI, dstI, wpos, srcs);
  k_agg1   <<<16*(NSUM/64), 256, 0, stream>>>(h1T, eps1, offA, srcs, z1);
  k_mm1    <<<NSUM/8,  256, 0, stream>>>(z1, W1a, b1a, W1b, b1b, h2T);
  k_agg2   <<<16*(NSUM/32), 256, 0, stream>>>(h2T, eps2, offA, srcs, z2);
  k_mm2    <<<NSUM/8,  256, 0, stream>>>(z2, W2a, b2a, W2b, b2b, (float*)d_out);
}